// Round 7
// baseline (269.458 us; speedup 1.0000x reference)
//
#include <hip/hip_runtime.h>
#include <math.h>

// VQ-VAE VectorQuantizer forward (fp16 MFMA, prefetched global feed, 2 dispatches):
//   x: [64,32,32,64] f32 -> N=65536 points, D=64
//   E: [D=64, K=1024] f32 (row-major: E[d*K + k])
// Outputs concatenated flat (float32):
//   quantized_st [N*D] | loss [1] | perplexity [1] | encoding_indices [N] (as float)
//
// dist_fast = ||e_k||^2 + BIAS - 2 f.e_k via MFMA f16 (x_f16 * (-2E)_f16,
// fp32 acc). A-frags stream from a prepacked global fp16 [k][d] image with
// explicit 1-tile-ahead software prefetch (launch_bounds(256,2) frees VGPRs
// for in-flight loads -- round-6 failure was VGPR=72 choking the pipeline).
// Index packed in low 8 mantissa bits; shuffle-based cross-quad merge; gated
// points re-resolved with the round-3-proven exact emulation of the np
// reference's fp32 arithmetic. Finalize runs in the last block (device-scope
// done counter) -- no separate kernel, no memset dispatch.

typedef __attribute__((ext_vector_type(8))) _Float16 half8v;
typedef __attribute__((ext_vector_type(4))) float float4v;
typedef unsigned short u16;
typedef unsigned int u32;

constexpr int D = 64;
constexpr int K = 1024;
constexpr int NPTS = 65536;
constexpr long QOFF = (long)NPTS * D;  // 4194304
constexpr float BIAS = 24.0f;          // dist+BIAS ~[3,48]: positive, pack-safe
constexpr float GATE = 2e-2f;          // fp16 5sigma + pack err + margin (r6-proven)
constexpr int GRID = 512;              // vq_main blocks (128 points each)

// ws layout (16B-aligned sections):
constexpr size_t OFF_LOSS = 0;                            // double
constexpr size_t OFF_DONE = 16;                           // int
constexpr size_t OFF_CNT  = 256;                          // int[1024]
constexpr size_t OFF_EC   = 4352;                         // float[1024] ref-order norms
constexpr size_t OFF_ECB  = 8448;                         // float[1024] norms + BIAS
constexpr size_t OFF_ET   = 12544;                        // float[1024*64] E^T [k][d]
constexpr size_t OFF_H16  = OFF_ET + (size_t)K * D * 4;   // _Float16[1024*64] -2E [k][d]

__device__ __forceinline__ float med3(float a, float b, float c) {
  return __builtin_amdgcn_fmed3f(a, b, c);
}

// Fused prep: zero accumulators + ref-order norms + fp32 transpose + fp16 -2E.
__global__ __launch_bounds__(256) void prep(const float* __restrict__ E,
                                            float* __restrict__ eC,
                                            float* __restrict__ eCb,
                                            float* __restrict__ Et,
                                            _Float16* __restrict__ h16,
                                            int* __restrict__ counts,
                                            double* __restrict__ lossSum,
                                            int* __restrict__ done) {
  const int gid = blockIdx.x * 256 + threadIdx.x;  // 16384 threads
  const int d = gid >> 8;
  const int k0 = (gid & 255) * 4;
  float4 v = *(const float4*)&E[d * K + k0];  // coalesced
  Et[(size_t)(k0 + 0) * 64 + d] = v.x;
  Et[(size_t)(k0 + 1) * 64 + d] = v.y;
  Et[(size_t)(k0 + 2) * 64 + d] = v.z;
  Et[(size_t)(k0 + 3) * 64 + d] = v.w;
  h16[(size_t)(k0 + 0) * 64 + d] = (_Float16)(-2.0f * v.x);
  h16[(size_t)(k0 + 1) * 64 + d] = (_Float16)(-2.0f * v.y);
  h16[(size_t)(k0 + 2) * 64 + d] = (_Float16)(-2.0f * v.z);
  h16[(size_t)(k0 + 3) * 64 + d] = (_Float16)(-2.0f * v.w);
  if (gid < K) {
    // np.sum(E**2, axis=0) order: sequential fp32 over d ascending (r3-proven)
    float c = __fmul_rn(E[gid], E[gid]);
#pragma unroll
    for (int dd = 1; dd < D; ++dd) {
      float e = E[dd * K + gid];
      c = __fadd_rn(c, __fmul_rn(e, e));
    }
    eC[gid] = c;
    eCb[gid] = c + BIAS;
    counts[gid] = 0;  // ws is 0xAA-poisoned each call: zero here (no memset dispatch)
  }
  if (gid == K) { *lossSum = 0.0; *done = 0; }
}

__global__ __launch_bounds__(256, 2) void vq_main(const float* __restrict__ x,
                                                  const float* __restrict__ E,
                                                  const _Float16* __restrict__ h16,
                                                  const float* __restrict__ eC,
                                                  const float* __restrict__ eCb,
                                                  const float* __restrict__ Etg,
                                                  float* __restrict__ out,
                                                  double* __restrict__ lossSum,
                                                  int* __restrict__ counts,
                                                  int* __restrict__ done) {
  __shared__ int bkbuf[128];
  __shared__ double shred[256];
  __shared__ int lastFlag;

  const int tid = threadIdx.x;
  const int w = tid >> 6;        // wave id: owns points w*32 .. w*32+31
  const int lane = tid & 63;
  const int col = lane & 15;     // A: code row m; B/C: point col n
  const int quad = lane >> 4;    // A/B: k-group; C: row-group
  const int blockBase = blockIdx.x * 128;
  const float INF = __builtin_inff();

  // ---- phase 1: load + convert x into fp16 B-fragments (registers) ----
  // B[k = s*32 + quad*8 + j][n = col], frag element j <-> d = s*32+quad*8+j.
  half8v Bf[2][2];
#pragma unroll
  for (int pt = 0; pt < 2; ++pt) {
    const float* xp = x + (size_t)(blockBase + w * 32 + pt * 16 + col) * 64;
#pragma unroll
    for (int s = 0; s < 2; ++s) {
      const float4* src = (const float4*)(xp + s * 32 + quad * 8);
      float4 a = src[0], b = src[1];
      half8v hf;
      hf[0] = (_Float16)a.x; hf[1] = (_Float16)a.y;
      hf[2] = (_Float16)a.z; hf[3] = (_Float16)a.w;
      hf[4] = (_Float16)b.x; hf[5] = (_Float16)b.y;
      hf[6] = (_Float16)b.z; hf[7] = (_Float16)b.w;
      Bf[pt][s] = hf;
    }
  }

  // running top-2 of packed biased distances, per point-tile
  float b1[2] = {INF, INF}, b2[2] = {INF, INF};

  // ---- phase 2: K loop, 64 code-tiles of 16, 1-tile-ahead prefetch ----
  half8v pA0[2], pA1[2];
  float4v pC[2];
  {
    const _Float16* ar = h16 + (size_t)col * 64 + quad * 8;
    pA0[0] = *(const half8v*)ar;
    pA1[0] = *(const half8v*)(ar + 32);
    pC[0] = *(const float4v*)&eCb[quad * 4];
  }
#pragma unroll 2
  for (int t = 0; t < 64; ++t) {
    const int s = t & 1, ns = s ^ 1;
    if (t < 63) {  // prefetch next tile while computing this one
      const _Float16* ar = h16 + (size_t)((t + 1) * 16 + col) * 64 + quad * 8;
      pA0[ns] = *(const half8v*)ar;
      pA1[ns] = *(const half8v*)(ar + 32);
      pC[ns] = *(const float4v*)&eCb[(t + 1) * 16 + quad * 4];
    }
#pragma unroll
    for (int pt = 0; pt < 2; ++pt) {
      float4v C = pC[s];
      C = __builtin_amdgcn_mfma_f32_16x16x32_f16(pA0[s], Bf[pt][0], C, 0, 0, 0);
      C = __builtin_amdgcn_mfma_f32_16x16x32_f16(pA1[s], Bf[pt][1], C, 0, 0, 0);
#pragma unroll
      for (int r = 0; r < 4; ++r) {
        // pack local id (t:6b | r:2b) into low 8 mantissa bits
        u32 u = (__float_as_uint(C[r]) & 0xffffff00u) | (u32)(t * 4 + r);
        float v = __uint_as_float(u);
        b2[pt] = med3(b1[pt], b2[pt], v);  // old b1 -> correct new second
        b1[pt] = fminf(b1[pt], v);
      }
    }
  }

  // ---- phase 3: shuffle merge across quads; lanes 0..31 own one point each ----
  // merged point = w*32 + lane; its pt = lane>>4, col-of-point = lane&15;
  // sources: lanes (lane&15) + 16q, their b1[pt], b2[pt].
  float sv[8];
  {
    const int scol = lane & 15;
#pragma unroll
    for (int P = 0; P < 2; ++P) {
      float v1 = b1[P], v2 = b2[P];
#pragma unroll
      for (int q = 0; q < 4; ++q) {
        float s1 = __shfl(v1, scol + 16 * q, 64);
        float s2 = __shfl(v2, scol + 16 * q, 64);
        if ((lane >> 4) == P) { sv[q] = s1; sv[4 + q] = s2; }
      }
    }
  }

  if (lane < 32) {
    float m1 = INF, m2 = INF;
#pragma unroll
    for (int j = 0; j < 8; ++j) {
      m2 = med3(m1, m2, sv[j]);
      m1 = fminf(m1, sv[j]);
    }
    // winner quad: which sv slot matched m1 (bit-exact compare)
    int qwin = 0;
#pragma unroll
    for (int j = 0; j < 8; ++j)
      if (__float_as_uint(sv[j]) == __float_as_uint(m1)) qwin = j & 3;
    u32 lb = __float_as_uint(m1) & 255u;
    int bestk = (int)((lb >> 2) * 16 + qwin * 4 + (lb & 3));
    const int myPoint = blockBase + w * 32 + lane;

    if (m2 - m1 < GATE) {
      // ----- exact emulation of the np reference's fp32 arithmetic -----
      const float* f = x + (size_t)myPoint * 64;
      float r8[8];
#pragma unroll
      for (int j = 0; j < 8; ++j) { float fv = f[j]; r8[j] = __fmul_rn(fv, fv); }
#pragma unroll
      for (int i = 8; i < D; i += 8)
#pragma unroll
        for (int j = 0; j < 8; ++j) {
          float fv = f[i + j];
          r8[j] = __fadd_rn(r8[j], __fmul_rn(fv, fv));
        }
      float A = __fadd_rn(__fadd_rn(__fadd_rn(r8[0], r8[1]), __fadd_rn(r8[2], r8[3])),
                          __fadd_rn(__fadd_rn(r8[4], r8[5]), __fadd_rn(r8[6], r8[7])));
      float bd = INF;
      int bkk = K;
#pragma unroll
      for (int c = 0; c < 8; ++c) {
        u32 cb = __float_as_uint(sv[c]) & 255u;
        int k = (int)((cb >> 2) * 16 + (c & 3) * 4 + (cb & 3));
        float m = 0.f;  // sequential fp32 fma over d (BLAS k-loop order)
#pragma unroll
        for (int d = 0; d < D; ++d) m = __fmaf_rn(f[d], E[d * K + k], m);
        float dist = __fadd_rn(__fsub_rn(A, __fmul_rn(2.f, m)), eC[k]);
        bool better = (dist < bd) || (dist == bd && k < bkk);
        bd = better ? dist : bd;
        bkk = better ? k : bkk;
      }
      bestk = bkk;
    }

    bkbuf[w * 32 + lane] = bestk;
    out[QOFF + 2 + myPoint] = (float)bestk;  // index (exact as float)
    atomicAdd(&counts[bestk], 1);
  }
  __syncthreads();

  // ---- phase 4: quantized write (gather from Et, coalesced) + loss ----
  const int pp = tid >> 1, half = tid & 1;
  const int bk = bkbuf[pp];
  const float4* et = (const float4*)(Etg + (size_t)bk * 64 + half * 32);
  const float4* xr = (const float4*)(x + (size_t)(blockBase + pp) * 64 + half * 32);
  float4* ov = (float4*)(out + (size_t)(blockBase + pp) * 64 + half * 32);
  float errs = 0.f;
#pragma unroll
  for (int i = 0; i < 8; ++i) {
    float4 qv = et[i];
    float4 xv = xr[i];
    float dx;
    dx = qv.x - xv.x; errs = fmaf(dx, dx, errs);
    dx = qv.y - xv.y; errs = fmaf(dx, dx, errs);
    dx = qv.z - xv.z; errs = fmaf(dx, dx, errs);
    dx = qv.w - xv.w; errs = fmaf(dx, dx, errs);
    ov[i] = qv;
  }
  double de = (double)errs;
#pragma unroll
  for (int off = 32; off > 0; off >>= 1) de += __shfl_down(de, off, 64);
  if (lane == 0) atomicAdd(lossSum, de);

  // ---- phase 5: last block finalizes loss + perplexity ----
  __syncthreads();
  __threadfence();
  if (tid == 0) {
    int old = __hip_atomic_fetch_add(done, 1, __ATOMIC_ACQ_REL,
                                     __HIP_MEMORY_SCOPE_AGENT);
    lastFlag = (old == GRID - 1);
  }
  __syncthreads();
  if (lastFlag) {
    double ent = 0.0;
    for (int k = tid; k < K; k += 256) {
      int c = __hip_atomic_load(&counts[k], __ATOMIC_RELAXED,
                                __HIP_MEMORY_SCOPE_AGENT);
      double pp2 = (double)c / (double)NPTS;
      ent += pp2 * log(pp2 + 1e-10);
    }
    shred[tid] = ent;
    __syncthreads();
    for (int s = 128; s > 0; s >>= 1) {
      if (tid < s) shred[tid] += shred[tid + s];
      __syncthreads();
    }
    if (tid == 0) {
      double ls = __hip_atomic_load(lossSum, __ATOMIC_RELAXED,
                                    __HIP_MEMORY_SCOPE_AGENT);
      // loss = q_latent + 0.25 * e_latent = 1.25 * mean((q - x)^2)
      out[QOFF + 0] = (float)(1.25 * ls / (double)((long)NPTS * D));
      out[QOFF + 1] = (float)exp(-shred[0]);  // perplexity
    }
  }
}

extern "C" void kernel_launch(void* const* d_in, const int* in_sizes, int n_in,
                              void* d_out, int out_size, void* d_ws, size_t ws_size,
                              hipStream_t stream) {
  const float* x = (const float*)d_in[0];
  const float* E = (const float*)d_in[1];
  float* out = (float*)d_out;

  char* ws = (char*)d_ws;
  double* lossSum = (double*)(ws + OFF_LOSS);
  int* done = (int*)(ws + OFF_DONE);
  int* counts = (int*)(ws + OFF_CNT);
  float* eC = (float*)(ws + OFF_EC);
  float* eCb = (float*)(ws + OFF_ECB);
  float* Etg = (float*)(ws + OFF_ET);
  _Float16* h16 = (_Float16*)(ws + OFF_H16);

  prep<<<64, 256, 0, stream>>>(E, eC, eCb, Etg, h16, counts, lossSum, done);
  vq_main<<<GRID, 256, 0, stream>>>(x, E, h16, eC, eCb, Etg, out, lossSum,
                                    counts, done);
}

// Round 8
// 183.710 us; speedup vs baseline: 1.4668x; 1.4668x over previous
//
#include <hip/hip_runtime.h>
#include <math.h>

// VQ-VAE VectorQuantizer forward (fp16 MFMA, LDS-staged swizzled codebook):
//   x: [64,32,32,64] f32 -> N=65536 points, D=64
//   E: [D=64, K=1024] f32 (row-major: E[d*K + k])
// Outputs concatenated flat (float32):
//   quantized_st [N*D] | loss [1] | perplexity [1] | encoding_indices [N] (as float)
//
// dist_fast = ||e_k||^2 + BIAS - 2 f.e_k via MFMA f16 (x_f16 * (-2E)_f16,
// fp32 acc). Codebook streamed through LDS in 4 chunks of 256 codes; the
// global fp16 image is PRE-SWIZZLED (dgroup dg of code k at ((dg+k)&7)) so
// staging is a linear coalesced copy and A-frag ds_read_b128s hit all 32
// banks at the structural floor. r6/r7 lesson: global-fed MFMA loops stall
// (~95%) regardless of prefetch games -- LDS is the proven path (r5).
// Index packed in low 8 mantissa bits; shuffle cross-quad merge (r7-proven);
// gated points re-resolved with the round-3-proven exact emulation of the np
// reference's fp32 arithmetic. Finalize in last block via ACQ_REL done
// counter -- NO threadfence (r7's fence caused a 14 MB L2-writeback storm).

typedef __attribute__((ext_vector_type(8))) _Float16 half8v;
typedef __attribute__((ext_vector_type(4))) float float4v;
typedef unsigned short u16;
typedef unsigned int u32;

constexpr int D = 64;
constexpr int K = 1024;
constexpr int NPTS = 65536;
constexpr long QOFF = (long)NPTS * D;  // 4194304
constexpr float BIAS = 24.0f;          // dist+BIAS ~[3,48]: positive, pack-safe
constexpr float GATE = 2e-2f;          // fp16 5sigma + pack err + margin (r6/r7-proven)
constexpr int GRID = 512;              // vq_main blocks (128 points each)
constexpr int CHUNK = 256;             // codes per LDS chunk

// ws layout (16B-aligned sections):
constexpr size_t OFF_LOSS = 0;                            // double
constexpr size_t OFF_DONE = 16;                           // int
constexpr size_t OFF_CNT  = 256;                          // int[1024]
constexpr size_t OFF_EC   = 4352;                         // float[1024] ref-order norms
constexpr size_t OFF_ECB  = 8448;                         // float[1024] norms + BIAS
constexpr size_t OFF_ET   = 12544;                        // float[1024*64] E^T [k][d]
constexpr size_t OFF_H16  = OFF_ET + (size_t)K * D * 4;   // _Float16[1024*64] swizzled -2E

__device__ __forceinline__ float med3(float a, float b, float c) {
  return __builtin_amdgcn_fmed3f(a, b, c);
}

// Fused prep: zero accumulators + ref-order norms + fp32 transpose + swizzled
// fp16 image of -2E (dgroup dg of code k stored at slot (dg+k)&7 within row k).
__global__ __launch_bounds__(256) void prep(const float* __restrict__ E,
                                            float* __restrict__ eC,
                                            float* __restrict__ eCb,
                                            float* __restrict__ Et,
                                            _Float16* __restrict__ h16,
                                            int* __restrict__ counts,
                                            double* __restrict__ lossSum,
                                            int* __restrict__ done) {
  const int gid = blockIdx.x * 256 + threadIdx.x;  // 16384 threads
  const int d = gid >> 8;
  const int k0 = (gid & 255) * 4;
  const int dg = d >> 3, dj = d & 7;
  float4 v = *(const float4*)&E[d * K + k0];  // coalesced
#pragma unroll
  for (int i = 0; i < 4; ++i) {
    int k = k0 + i;
    float e = (i == 0) ? v.x : (i == 1) ? v.y : (i == 2) ? v.z : v.w;
    Et[(size_t)k * 64 + d] = e;
    h16[(size_t)k * 64 + ((dg + k) & 7) * 8 + dj] = (_Float16)(-2.0f * e);
  }
  if (gid < K) {
    // np.sum(E**2, axis=0) order: sequential fp32 over d ascending (r3-proven)
    float c = __fmul_rn(E[gid], E[gid]);
#pragma unroll
    for (int dd = 1; dd < D; ++dd) {
      float e = E[dd * K + gid];
      c = __fadd_rn(c, __fmul_rn(e, e));
    }
    eC[gid] = c;
    eCb[gid] = c + BIAS;
    counts[gid] = 0;  // ws is 0xAA-poisoned each call: zero here (no memset dispatch)
  }
  if (gid == K) { *lossSum = 0.0; *done = 0; }
}

__global__ __launch_bounds__(256, 4) void vq_main(const float* __restrict__ x,
                                                  const float* __restrict__ E,
                                                  const _Float16* __restrict__ h16,
                                                  const float* __restrict__ eC,
                                                  const float* __restrict__ eCbG,
                                                  const float* __restrict__ Etg,
                                                  float* __restrict__ out,
                                                  double* __restrict__ lossSum,
                                                  int* __restrict__ counts,
                                                  int* __restrict__ done) {
  __shared__ __align__(16) u16 Abuf[CHUNK * 64];   // 32 KB, swizzled rows
  __shared__ __align__(16) float eCbL[CHUNK];      // 1 KB
  __shared__ int bkbuf[128];
  __shared__ double shred[256];
  __shared__ int lastFlag;

  const int tid = threadIdx.x;
  const int w = tid >> 6;        // wave id: owns points w*32 .. w*32+31
  const int lane = tid & 63;
  const int col = lane & 15;     // A: code row m; B/C: point col n
  const int quad = lane >> 4;    // A/B: k-group; C: row-group
  const int blockBase = blockIdx.x * 128;
  const float INF = __builtin_inff();

  // ---- phase 1: load + convert x into fp16 B-fragments (registers) ----
  // B[k = s*32 + quad*8 + j][n = col], frag element j <-> d = s*32+quad*8+j.
  half8v Bf[2][2];
#pragma unroll
  for (int pt = 0; pt < 2; ++pt) {
    const float* xp = x + (size_t)(blockBase + w * 32 + pt * 16 + col) * 64;
#pragma unroll
    for (int s = 0; s < 2; ++s) {
      const float4* src = (const float4*)(xp + s * 32 + quad * 8);
      float4 a = src[0], b = src[1];
      half8v hf;
      hf[0] = (_Float16)a.x; hf[1] = (_Float16)a.y;
      hf[2] = (_Float16)a.z; hf[3] = (_Float16)a.w;
      hf[4] = (_Float16)b.x; hf[5] = (_Float16)b.y;
      hf[6] = (_Float16)b.z; hf[7] = (_Float16)b.w;
      Bf[pt][s] = hf;
    }
  }

  // running top-2 of packed biased distances, per point-tile
  float b1[2] = {INF, INF}, b2[2] = {INF, INF};

  // tile-invariant swizzle offsets (16 = 0 mod 8 => depends only on quad+col)
  const int swz0 = ((quad + col) & 7) * 8;        // dgroup quad   (d = quad*8+j)
  const int swz1 = ((quad + 4 + col) & 7) * 8;    // dgroup quad+4 (d = 32+quad*8+j)

  // ---- phase 2: K loop, 4 LDS chunks of 256 codes ----
  for (int ch = 0; ch < 4; ++ch) {
    __syncthreads();  // protect Abuf reuse
    // stage 32 KB: linear coalesced copy (image is pre-swizzled)
    const float4* src = (const float4*)(h16 + (size_t)ch * CHUNK * 64);
#pragma unroll
    for (int r = 0; r < 8; ++r) {
      int idx = r * 256 + tid;
      *(float4*)&Abuf[idx * 8] = src[idx];
    }
    if (tid < 64) *(float4*)&eCbL[tid * 4] = *(const float4*)&eCbG[ch * CHUNK + tid * 4];
    __syncthreads();

#pragma unroll
    for (int ct = 0; ct < 16; ++ct) {  // 16 code-tiles of 16
      const u16* arow = &Abuf[(ct * 16 + col) * 64];
      half8v A0 = *(const half8v*)&arow[swz0];
      half8v A1 = *(const half8v*)&arow[swz1];
      float4v Ci = *(const float4v*)&eCbL[ct * 16 + quad * 4];
      const int t = ch * 16 + ct;
#pragma unroll
      for (int pt = 0; pt < 2; ++pt) {
        float4v C = Ci;
        C = __builtin_amdgcn_mfma_f32_16x16x32_f16(A0, Bf[pt][0], C, 0, 0, 0);
        C = __builtin_amdgcn_mfma_f32_16x16x32_f16(A1, Bf[pt][1], C, 0, 0, 0);
#pragma unroll
        for (int r = 0; r < 4; ++r) {
          // pack local id (t:6b | r:2b) into low 8 mantissa bits
          u32 u = (__float_as_uint(C[r]) & 0xffffff00u) | (u32)(t * 4 + r);
          float v = __uint_as_float(u);
          b2[pt] = med3(b1[pt], b2[pt], v);  // old b1 -> correct new second
          b1[pt] = fminf(b1[pt], v);
        }
      }
    }
  }

  // ---- phase 3: shuffle merge across quads; lanes 0..31 own one point each ----
  float sv[8];
  {
    const int scol = lane & 15;
#pragma unroll
    for (int P = 0; P < 2; ++P) {
      float v1 = b1[P], v2 = b2[P];
#pragma unroll
      for (int q = 0; q < 4; ++q) {
        float s1 = __shfl(v1, scol + 16 * q, 64);
        float s2 = __shfl(v2, scol + 16 * q, 64);
        if ((lane >> 4) == P) { sv[q] = s1; sv[4 + q] = s2; }
      }
    }
  }

  if (lane < 32) {
    float m1 = INF, m2 = INF;
#pragma unroll
    for (int j = 0; j < 8; ++j) {
      m2 = med3(m1, m2, sv[j]);
      m1 = fminf(m1, sv[j]);
    }
    int qwin = 0;
#pragma unroll
    for (int j = 0; j < 8; ++j)
      if (__float_as_uint(sv[j]) == __float_as_uint(m1)) qwin = j & 3;
    u32 lb = __float_as_uint(m1) & 255u;
    int bestk = (int)((lb >> 2) * 16 + qwin * 4 + (lb & 3));
    const int myPoint = blockBase + w * 32 + lane;

    if (m2 - m1 < GATE) {
      // ----- exact emulation of the np reference's fp32 arithmetic -----
      const float* f = x + (size_t)myPoint * 64;
      float r8[8];
#pragma unroll
      for (int j = 0; j < 8; ++j) { float fv = f[j]; r8[j] = __fmul_rn(fv, fv); }
#pragma unroll
      for (int i = 8; i < D; i += 8)
#pragma unroll
        for (int j = 0; j < 8; ++j) {
          float fv = f[i + j];
          r8[j] = __fadd_rn(r8[j], __fmul_rn(fv, fv));
        }
      float A = __fadd_rn(__fadd_rn(__fadd_rn(r8[0], r8[1]), __fadd_rn(r8[2], r8[3])),
                          __fadd_rn(__fadd_rn(r8[4], r8[5]), __fadd_rn(r8[6], r8[7])));
      float bd = INF;
      int bkk = K;
#pragma unroll
      for (int c = 0; c < 8; ++c) {
        u32 cb = __float_as_uint(sv[c]) & 255u;
        int k = (int)((cb >> 2) * 16 + (c & 3) * 4 + (cb & 3));
        float m = 0.f;  // sequential fp32 fma over d (BLAS k-loop order)
#pragma unroll
        for (int d = 0; d < D; ++d) m = __fmaf_rn(f[d], E[d * K + k], m);
        float dist = __fadd_rn(__fsub_rn(A, __fmul_rn(2.f, m)), eC[k]);
        bool better = (dist < bd) || (dist == bd && k < bkk);
        bd = better ? dist : bd;
        bkk = better ? k : bkk;
      }
      bestk = bkk;
    }

    bkbuf[w * 32 + lane] = bestk;
    out[QOFF + 2 + myPoint] = (float)bestk;  // index (exact as float)
    atomicAdd(&counts[bestk], 1);
  }
  __syncthreads();

  // ---- phase 4: quantized write (gather from Et, coalesced) + loss ----
  const int pp = tid >> 1, half = tid & 1;
  const int bk = bkbuf[pp];
  const float4* et = (const float4*)(Etg + (size_t)bk * 64 + half * 32);
  const float4* xr = (const float4*)(x + (size_t)(blockBase + pp) * 64 + half * 32);
  float4* ov = (float4*)(out + (size_t)(blockBase + pp) * 64 + half * 32);
  float errs = 0.f;
#pragma unroll
  for (int i = 0; i < 8; ++i) {
    float4 qv = et[i];
    float4 xv = xr[i];
    float dx;
    dx = qv.x - xv.x; errs = fmaf(dx, dx, errs);
    dx = qv.y - xv.y; errs = fmaf(dx, dx, errs);
    dx = qv.z - xv.z; errs = fmaf(dx, dx, errs);
    dx = qv.w - xv.w; errs = fmaf(dx, dx, errs);
    ov[i] = qv;
  }
  double de = (double)errs;
#pragma unroll
  for (int off = 32; off > 0; off >>= 1) de += __shfl_down(de, off, 64);
  if (lane == 0) atomicAdd(lossSum, de);

  // ---- phase 5: last block finalizes loss + perplexity (no threadfence:
  // counts/lossSum are device-scope atomics; ACQ_REL on done orders them) ----
  __syncthreads();
  if (tid == 0) {
    int old = __hip_atomic_fetch_add(done, 1, __ATOMIC_ACQ_REL,
                                     __HIP_MEMORY_SCOPE_AGENT);
    lastFlag = (old == GRID - 1);
  }
  __syncthreads();
  if (lastFlag) {
    double ent = 0.0;
    for (int k = tid; k < K; k += 256) {
      int c = __hip_atomic_load(&counts[k], __ATOMIC_RELAXED,
                                __HIP_MEMORY_SCOPE_AGENT);
      double pp2 = (double)c / (double)NPTS;
      ent += pp2 * log(pp2 + 1e-10);
    }
    shred[tid] = ent;
    __syncthreads();
    for (int s = 128; s > 0; s >>= 1) {
      if (tid < s) shred[tid] += shred[tid + s];
      __syncthreads();
    }
    if (tid == 0) {
      double ls = __hip_atomic_load(lossSum, __ATOMIC_RELAXED,
                                    __HIP_MEMORY_SCOPE_AGENT);
      // loss = q_latent + 0.25 * e_latent = 1.25 * mean((q - x)^2)
      out[QOFF + 0] = (float)(1.25 * ls / (double)((long)NPTS * D));
      out[QOFF + 1] = (float)exp(-shred[0]);  // perplexity
    }
  }
}

extern "C" void kernel_launch(void* const* d_in, const int* in_sizes, int n_in,
                              void* d_out, int out_size, void* d_ws, size_t ws_size,
                              hipStream_t stream) {
  const float* x = (const float*)d_in[0];
  const float* E = (const float*)d_in[1];
  float* out = (float*)d_out;

  char* ws = (char*)d_ws;
  double* lossSum = (double*)(ws + OFF_LOSS);
  int* done = (int*)(ws + OFF_DONE);
  int* counts = (int*)(ws + OFF_CNT);
  float* eC = (float*)(ws + OFF_EC);
  float* eCb = (float*)(ws + OFF_ECB);
  float* Etg = (float*)(ws + OFF_ET);
  _Float16* h16 = (_Float16*)(ws + OFF_H16);

  prep<<<64, 256, 0, stream>>>(E, eC, eCb, Etg, h16, counts, lossSum, done);
  vq_main<<<GRID, 256, 0, stream>>>(x, E, h16, eC, eCb, Etg, out, lossSum,
                                    counts, done);
}